// Round 1
// 2385.942 us; speedup vs baseline: 1.0789x; 1.0789x over previous
//
#include <hip/hip_runtime.h>
#include <hip/hip_fp16.h>

// Problem constants
#define MTOK 8192   // B*S
#define DDIM 4096   // D
#define IDIM 11008  // I

// GEMM tiling: 256(m) x 128(n-per-stream) tile, BK=64, 512 threads (8 waves)
#define BM 256
#define BN 128
#define BK 64
#define NTHR 512

typedef _Float16 f16x4 __attribute__((ext_vector_type(4)));
typedef _Float16 f16x8 __attribute__((ext_vector_type(8)));
typedef float    f32x4 __attribute__((ext_vector_type(4)));

// ---------------- conversion kernels ----------------
__global__ __launch_bounds__(256) void cvt_x_kernel(const float* __restrict__ src,
                                                    _Float16* __restrict__ dst, int n4) {
  int stride = gridDim.x * blockDim.x;
  for (int i = blockIdx.x * blockDim.x + threadIdx.x; i < n4; i += stride) {
    float4 v = ((const float4*)src)[i];
    f16x4 h;
    h.x = (_Float16)v.x; h.y = (_Float16)v.y; h.z = (_Float16)v.z; h.w = (_Float16)v.w;
    ((f16x4*)dst)[i] = h;
  }
}

__global__ __launch_bounds__(256) void cvt_w_kernel(const int* __restrict__ src,
                                                    _Float16* __restrict__ dst, int n4) {
  int stride = gridDim.x * blockDim.x;
  for (int i = blockIdx.x * blockDim.x + threadIdx.x; i < n4; i += stride) {
    int4 v = ((const int4*)src)[i];
    f16x4 h;  // int8-range values are exact in f16
    h.x = (_Float16)v.x; h.y = (_Float16)v.y; h.z = (_Float16)v.z; h.w = (_Float16)v.w;
    ((f16x4*)dst)[i] = h;
  }
}

// ---------------- GEMM helpers ----------------
// LDS tile layout: [row][chunk 0..7], chunk = 8 f16 = 16B.
// Chunk at LDS (r, c) holds global chunk (r, c ^ (r&7)).
// -> global_load_lds stays lane-contiguous (dest must be linear) while
//    frag reads are conflict-free (measured 0 SQ_LDS_BANK_CONFLICT).
template<int ROWS>
__device__ __forceinline__ void stage_tile(const _Float16* __restrict__ gbase, int ldk,
                                           _Float16* stile, int tid) {
#pragma unroll
  for (int it = 0; it < (ROWS * 8) / NTHR; ++it) {
    int slot = it * NTHR + tid;          // chunks of 16B
    int r = slot >> 3, c = slot & 7;
    int csrc = c ^ (r & 7);
    const _Float16* gp = gbase + (long)r * ldk + csrc * 8;
    __builtin_amdgcn_global_load_lds(
        (const __attribute__((address_space(1))) void*)gp,
        (__attribute__((address_space(3))) void*)(stile + slot * 8),
        16, 0, 0);
  }
}

__device__ __forceinline__ f16x8 frag_ld(const _Float16* s, int row, int cbase) {
  int c = cbase ^ (row & 7);
  return *(const f16x8*)(s + (row * 8 + c) * 8);
}

// ---------------- fused gate/up GEMM + SwiGLU epilogue ----------------
// X:[MTOK,DDIM] f16, Wg/Wu:[IDIM,DDIM] f16 (B^T form), H:[MTOK,IDIM] f16 scaled by 1/256
// 2-phase double-buffered pipeline: stage(t+1) issued before compute(t);
// vmcnt drained only AFTER compute (raw s_barrier, no compiler vmcnt(0) drain).
__global__ __launch_bounds__(NTHR, 2) void gemm_gateup(
    const _Float16* __restrict__ X, const _Float16* __restrict__ Wg,
    const _Float16* __restrict__ Wu, const float* __restrict__ gs_p,
    const float* __restrict__ us_p, _Float16* __restrict__ H) {
  constexpr int ASZ = BM * BK;        // 16384 f16
  constexpr int BSZ = BN * BK;        // 8192 f16
  constexpr int BUF = ASZ + 2 * BSZ;  // 32768 f16 = 64 KiB
  __shared__ _Float16 lds[2 * BUF] __attribute__((aligned(16)));  // 128 KiB

  int tid = threadIdx.x;
  int bm = blockIdx.x, bn = blockIdx.y;
  int lane = tid & 63, w = tid >> 6;          // 8 waves: 4(m) x 2(n)
  int wm = (w >> 1) * 64, wn = (w & 1) * 64;  // per-wave 64x64 per stream
  int lr = lane & 15, q = lane >> 4;

  const _Float16* Abase = X + (long)bm * BM * DDIM;
  const _Float16* Gbase = Wg + (long)bn * BN * DDIM;
  const _Float16* Ubase = Wu + (long)bn * BN * DDIM;

  f32x4 accg[4][4], accu[4][4];
#pragma unroll
  for (int i = 0; i < 4; ++i)
#pragma unroll
    for (int j = 0; j < 4; ++j) {
      accg[i][j] = (f32x4){0.f, 0.f, 0.f, 0.f};
      accu[i][j] = (f32x4){0.f, 0.f, 0.f, 0.f};
    }

  // prologue: stage tile 0, full drain
  stage_tile<BM>(Abase, DDIM, lds, tid);
  stage_tile<BN>(Gbase, DDIM, lds + ASZ, tid);
  stage_tile<BN>(Ubase, DDIM, lds + ASZ + BSZ, tid);
  asm volatile("s_waitcnt vmcnt(0)" ::: "memory");
  __builtin_amdgcn_s_barrier();

  constexpr int NT = DDIM / BK;  // 64
#pragma unroll 1
  for (int t = 0; t < NT; ++t) {
    _Float16* cb = lds + (t & 1) * BUF;
    if (t + 1 < NT) {  // issue next-tile loads FIRST; they fly during MFMA
      _Float16* nb = lds + ((t + 1) & 1) * BUF;
      int k0 = (t + 1) * BK;
      stage_tile<BM>(Abase + k0, DDIM, nb, tid);
      stage_tile<BN>(Gbase + k0, DDIM, nb + ASZ, tid);
      stage_tile<BN>(Ubase + k0, DDIM, nb + ASZ + BSZ, tid);
    }
#pragma unroll
    for (int kk = 0; kk < 2; ++kk) {
      int cbase = kk * 4 + q;  // 16B chunk index for k = kk*32 + q*8
      f16x8 a[4], bg[4], bu[4];
#pragma unroll
      for (int i = 0; i < 4; ++i) a[i] = frag_ld(cb, wm + i * 16 + lr, cbase);
#pragma unroll
      for (int j = 0; j < 4; ++j) {
        bg[j] = frag_ld(cb + ASZ, wn + j * 16 + lr, cbase);
        bu[j] = frag_ld(cb + ASZ + BSZ, wn + j * 16 + lr, cbase);
      }
#pragma unroll
      for (int i = 0; i < 4; ++i)
#pragma unroll
        for (int j = 0; j < 4; ++j) {
          accg[i][j] = __builtin_amdgcn_mfma_f32_16x16x32_f16(a[i], bg[j], accg[i][j], 0, 0, 0);
          accu[i][j] = __builtin_amdgcn_mfma_f32_16x16x32_f16(a[i], bu[j], accu[i][j], 0, 0, 0);
        }
    }
    // drain next-tile loads AFTER compute (latency hidden under 64 MFMA/wave),
    // one barrier per K-step: next iter's stage may then overwrite cb.
    asm volatile("s_waitcnt vmcnt(0)" ::: "memory");
    __builtin_amdgcn_s_barrier();
  }

  float gs = gs_p[0], us = us_p[0];
  // C/D layout (verified, dtype-independent): col = lane&15, row = q*4 + reg
#pragma unroll
  for (int i = 0; i < 4; ++i)
#pragma unroll
    for (int j = 0; j < 4; ++j)
#pragma unroll
      for (int r = 0; r < 4; ++r) {
        long m = (long)bm * BM + wm + i * 16 + q * 4 + r;
        long n = (long)bn * BN + wn + j * 16 + lr;
        float g = accg[i][j][r] * gs;
        float u = accu[i][j][r] * us;
        float sg = g / (1.0f + __expf(-g));  // silu
        H[m * IDIM + n] = (_Float16)(sg * u * 0.00390625f);  // /256 keeps f16 range safe
      }
}

// ---------------- down-proj GEMM (paired-BN: one A tile, two B panels) ----------------
// Hin:[MTOK,IDIM] f16 (scaled 1/256), Wd:[DDIM,IDIM] f16, Out:[MTOK,DDIM] f32
// Same 2-phase pipelined structure; 256(m) x 256(n) output tile per block.
__global__ __launch_bounds__(NTHR, 2) void gemm_down(
    const _Float16* __restrict__ Hin, const _Float16* __restrict__ Wd,
    const float* __restrict__ ds_p, float* __restrict__ Out) {
  constexpr int ASZ = BM * BK;
  constexpr int BSZ = BN * BK;
  constexpr int BUF = ASZ + 2 * BSZ;
  __shared__ _Float16 lds[2 * BUF] __attribute__((aligned(16)));  // 128 KiB

  int tid = threadIdx.x;
  int bm = blockIdx.x, bn = blockIdx.y;
  int lane = tid & 63, w = tid >> 6;
  int wm = (w >> 1) * 64, wn = (w & 1) * 64;
  int lr = lane & 15, q = lane >> 4;

  const _Float16* Abase  = Hin + (long)bm * BM * IDIM;
  const _Float16* B0base = Wd + (long)(bn * 256) * IDIM;
  const _Float16* B1base = Wd + (long)(bn * 256 + 128) * IDIM;

  f32x4 acc0[4][4], acc1[4][4];
#pragma unroll
  for (int i = 0; i < 4; ++i)
#pragma unroll
    for (int j = 0; j < 4; ++j) {
      acc0[i][j] = (f32x4){0.f, 0.f, 0.f, 0.f};
      acc1[i][j] = (f32x4){0.f, 0.f, 0.f, 0.f};
    }

  stage_tile<BM>(Abase, IDIM, lds, tid);
  stage_tile<BN>(B0base, IDIM, lds + ASZ, tid);
  stage_tile<BN>(B1base, IDIM, lds + ASZ + BSZ, tid);
  asm volatile("s_waitcnt vmcnt(0)" ::: "memory");
  __builtin_amdgcn_s_barrier();

  constexpr int NT = IDIM / BK;  // 172
#pragma unroll 1
  for (int t = 0; t < NT; ++t) {
    _Float16* cb = lds + (t & 1) * BUF;
    if (t + 1 < NT) {
      _Float16* nb = lds + ((t + 1) & 1) * BUF;
      int k0 = (t + 1) * BK;
      stage_tile<BM>(Abase + k0, IDIM, nb, tid);
      stage_tile<BN>(B0base + k0, IDIM, nb + ASZ, tid);
      stage_tile<BN>(B1base + k0, IDIM, nb + ASZ + BSZ, tid);
    }
#pragma unroll
    for (int kk = 0; kk < 2; ++kk) {
      int cbase = kk * 4 + q;
      f16x8 a[4], b0[4], b1[4];
#pragma unroll
      for (int i = 0; i < 4; ++i) a[i] = frag_ld(cb, wm + i * 16 + lr, cbase);
#pragma unroll
      for (int j = 0; j < 4; ++j) {
        b0[j] = frag_ld(cb + ASZ, wn + j * 16 + lr, cbase);
        b1[j] = frag_ld(cb + ASZ + BSZ, wn + j * 16 + lr, cbase);
      }
#pragma unroll
      for (int i = 0; i < 4; ++i)
#pragma unroll
        for (int j = 0; j < 4; ++j) {
          acc0[i][j] = __builtin_amdgcn_mfma_f32_16x16x32_f16(a[i], b0[j], acc0[i][j], 0, 0, 0);
          acc1[i][j] = __builtin_amdgcn_mfma_f32_16x16x32_f16(a[i], b1[j], acc1[i][j], 0, 0, 0);
        }
    }
    asm volatile("s_waitcnt vmcnt(0)" ::: "memory");
    __builtin_amdgcn_s_barrier();
  }

  float scale = ds_p[0] * 256.0f;  // undo the 1/256 on H
#pragma unroll
  for (int i = 0; i < 4; ++i)
#pragma unroll
    for (int j = 0; j < 4; ++j)
#pragma unroll
      for (int r = 0; r < 4; ++r) {
        long m = (long)bm * BM + wm + i * 16 + q * 4 + r;
        long n = (long)bn * 256 + wn + j * 16 + lr;
        Out[m * DDIM + n] = acc0[i][j][r] * scale;
        Out[m * DDIM + n + 128] = acc1[i][j][r] * scale;
      }
}

// ---------------- launch ----------------
// ws layout (bytes):
//   x_f16:   [0,          67108864)
//   gate_f16:[67108864,   157286400)
//   up_f16:  [157286400,  247463936)
//   down_f16:[247463936,  337641472)
//   h_f16:   [337641472,  517996544)
extern "C" void kernel_launch(void* const* d_in, const int* in_sizes, int n_in,
                              void* d_out, int out_size, void* d_ws, size_t ws_size,
                              hipStream_t stream) {
  const float* x  = (const float*)d_in[0];
  const int*   gw = (const int*)d_in[1];
  const float* gs = (const float*)d_in[2];
  const int*   uw = (const int*)d_in[3];
  const float* us = (const float*)d_in[4];
  const int*   dw = (const int*)d_in[5];
  const float* ds = (const float*)d_in[6];
  float* out = (float*)d_out;

  char* ws = (char*)d_ws;
  _Float16* xf  = (_Float16*)(ws);
  _Float16* gwf = (_Float16*)(ws + 67108864L);
  _Float16* uwf = (_Float16*)(ws + 157286400L);
  _Float16* dwf = (_Float16*)(ws + 247463936L);
  _Float16* h   = (_Float16*)(ws + 337641472L);

  cvt_x_kernel<<<2048, 256, 0, stream>>>(x, xf, (MTOK * DDIM) / 4);
  cvt_w_kernel<<<2048, 256, 0, stream>>>(gw, gwf, (IDIM * DDIM) / 4);
  cvt_w_kernel<<<2048, 256, 0, stream>>>(uw, uwf, (IDIM * DDIM) / 4);
  cvt_w_kernel<<<2048, 256, 0, stream>>>(dw, dwf, (DDIM * IDIM) / 4);

  dim3 g1(MTOK / BM, IDIM / BN);  // 32 x 86
  gemm_gateup<<<g1, NTHR, 0, stream>>>(xf, gwf, uwf, gs, us, h);

  dim3 g2(MTOK / BM, DDIM / 256);  // 32 x 16
  gemm_down<<<g2, NTHR, 0, stream>>>(h, dwf, ds, out);
}